// Round 1
// baseline (2963.335 us; speedup 1.0000x reference)
//
#include <hip/hip_runtime.h>

#define N_NODES 100000
#define N_EDGES 1600000
#define F 128

// ---------------- Phase 1: scatter-add SpMM over COO edges ----------------
// 32 threads per edge; each thread handles 4 contiguous floats (float4).
// LE[dst,:] += val * feats[src,:]
__global__ __launch_bounds__(256) void scatter_kernel(
    const int* __restrict__ esrc, const int* __restrict__ edst,
    const float* __restrict__ evals, const float* __restrict__ feats,
    float* __restrict__ LE)
{
    int t = blockIdx.x * 256 + threadIdx.x;
    int e = t >> 5;               // edge index
    if (e >= N_EDGES) return;
    int c = t & 31;               // float4 chunk within the 128-wide row
    int s = esrc[e];
    int d = edst[e];
    float v = evals[e];
    const float4* fr = (const float4*)(feats + (size_t)s * F);
    float4 f = fr[c];
    float* o = LE + (size_t)d * F + c * 4;
    atomicAdd(o + 0, v * f.x);
    atomicAdd(o + 1, v * f.y);
    atomicAdd(o + 2, v * f.z);
    atomicAdd(o + 3, v * f.w);
}

// ---------------- Phase 2: fused dual dense layer ----------------
// out[n,j] = sum_k (LE+f)[n,k]*W1[j,k] + (LE*f)[n,k]*W2[j,k] + b1[j] + b2[j]
// 32 nodes per block, 256 threads, 4 nodes x 4 feats register tile per thread.
#define NT 32   // nodes per block
#define KC 16   // k-chunk staged in LDS
#define WPAD 4  // pad W rows to 132 floats: bank-spread + keeps float4 16B-aligned

__global__ __launch_bounds__(256) void fused_mlp_kernel(
    const float* __restrict__ LE, const float* __restrict__ feats,
    const float* __restrict__ W1, const float* __restrict__ b1,
    const float* __restrict__ W2, const float* __restrict__ b2,
    float* __restrict__ out)
{
    __shared__ float sA[NT][F];          // LE + feats
    __shared__ float sC[NT][F];          // LE * feats
    __shared__ float sW1[KC][F + WPAD];  // sW1[kk][j] = W1[j][k0+kk]
    __shared__ float sW2[KC][F + WPAD];

    const int t  = threadIdx.x;
    const int jt = t & 31;   // output features 4*jt .. 4*jt+3
    const int g  = t >> 5;   // node group: nodes 4*g .. 4*g+3
    const int node0 = blockIdx.x * NT;

    // Stage A and C tiles (coalesced; 4096 elems each, 256 threads).
    for (int i = t; i < NT * F; i += 256) {
        int nl = i >> 7;       // local node
        int k  = i & 127;
        int n  = node0 + nl;
        float le = 0.f, ft = 0.f;
        if (n < N_NODES) {
            le = LE[(size_t)n * F + k];
            ft = feats[(size_t)n * F + k];
        }
        sA[nl][k] = le + ft;
        sC[nl][k] = le * ft;
    }

    float acc[4][4];
#pragma unroll
    for (int a = 0; a < 4; a++)
#pragma unroll
        for (int b = 0; b < 4; b++) acc[a][b] = 0.f;

    for (int k0 = 0; k0 < F; k0 += KC) {
        __syncthreads();  // protect sW from prior readers; covers A/C staging on iter 0
        // Stage transposed W chunks: sW[kk][j] = W[j*F + k0 + kk]
        for (int i = t; i < KC * F; i += 256) {
            int j  = i >> 4;     // / KC
            int kk = i & (KC - 1);
            sW1[kk][j] = W1[(size_t)j * F + k0 + kk];
            sW2[kk][j] = W2[(size_t)j * F + k0 + kk];
        }
        __syncthreads();

#pragma unroll
        for (int kk = 0; kk < KC; kk++) {
            const int k = k0 + kk;
            float4 w1 = *(const float4*)&sW1[kk][4 * jt];
            float4 w2 = *(const float4*)&sW2[kk][4 * jt];
#pragma unroll
            for (int nn = 0; nn < 4; nn++) {
                float a = sA[4 * g + nn][k];
                float c = sC[4 * g + nn][k];
                acc[nn][0] += a * w1.x + c * w2.x;
                acc[nn][1] += a * w1.y + c * w2.y;
                acc[nn][2] += a * w1.z + c * w2.z;
                acc[nn][3] += a * w1.w + c * w2.w;
            }
        }
    }

    // Epilogue: add biases, store float4 per node.
    const int j0 = 4 * jt;
    float4 bb;
    bb.x = b1[j0 + 0] + b2[j0 + 0];
    bb.y = b1[j0 + 1] + b2[j0 + 1];
    bb.z = b1[j0 + 2] + b2[j0 + 2];
    bb.w = b1[j0 + 3] + b2[j0 + 3];
#pragma unroll
    for (int nn = 0; nn < 4; nn++) {
        int n = node0 + 4 * g + nn;
        if (n < N_NODES) {
            float4 o;
            o.x = acc[nn][0] + bb.x;
            o.y = acc[nn][1] + bb.y;
            o.z = acc[nn][2] + bb.z;
            o.w = acc[nn][3] + bb.w;
            *(float4*)(out + (size_t)n * F + j0) = o;
        }
    }
}

extern "C" void kernel_launch(void* const* d_in, const int* in_sizes, int n_in,
                              void* d_out, int out_size, void* d_ws, size_t ws_size,
                              hipStream_t stream) {
    const int*   edge_src  = (const int*)d_in[0];
    const int*   edge_dst  = (const int*)d_in[1];
    const float* edge_vals = (const float*)d_in[2];
    const float* feats     = (const float*)d_in[3];
    const float* W1        = (const float*)d_in[4];
    const float* b1        = (const float*)d_in[5];
    const float* W2        = (const float*)d_in[6];
    const float* b2        = (const float*)d_in[7];
    float* out = (float*)d_out;
    float* LE  = (float*)d_ws;   // N_NODES * F floats = 51.2 MB

    // Zero the LE accumulator (ws is poisoned 0xAA before every call).
    hipMemsetAsync(LE, 0, (size_t)N_NODES * F * sizeof(float), stream);

    // Phase 1: scatter-add over edges.
    int scatter_blocks = (N_EDGES * 32 + 255) / 256;
    scatter_kernel<<<scatter_blocks, 256, 0, stream>>>(edge_src, edge_dst,
                                                       edge_vals, feats, LE);

    // Phase 2: fused dual-GEMM epilogue.
    int mlp_blocks = (N_NODES + NT - 1) / NT;
    fused_mlp_kernel<<<mlp_blocks, 256, 0, stream>>>(LE, feats, W1, b1, W2, b2, out);
}

// Round 2
// 649.208 us; speedup vs baseline: 4.5645x; 4.5645x over previous
//
#include <hip/hip_runtime.h>

#define N_NODES 100000
#define N_EDGES 1600000
#define F 128

// ============ CSR build ============

__global__ __launch_bounds__(256) void hist_kernel(
    const int* __restrict__ edst, int* __restrict__ counts)
{
    int e = blockIdx.x * 256 + threadIdx.x;
    if (e < N_EDGES) atomicAdd(&counts[edst[e]], 1);
}

// Single-workgroup exclusive scan of counts[N_NODES] -> row_off, cursor.
// 1024 threads, chunked; wave shfl scan + cross-wave LDS scan + running carry.
__global__ __launch_bounds__(1024) void scan_kernel(
    const int* __restrict__ counts, int* __restrict__ row_off,
    int* __restrict__ cursor)
{
    __shared__ int wsum[16];
    const int t = threadIdx.x;
    const int lane = t & 63;
    const int w = t >> 6;
    int carry = 0;
    for (int base = 0; base < N_NODES; base += 1024) {
        int i = base + t;
        int x = (i < N_NODES) ? counts[i] : 0;
        // intra-wave inclusive scan
        int v = x;
#pragma unroll
        for (int d = 1; d < 64; d <<= 1) {
            int y = __shfl_up(v, d);
            if (lane >= d) v += y;
        }
        if (lane == 63) wsum[w] = v;
        __syncthreads();
        if (w == 0 && lane < 16) {
            int s = wsum[lane];
#pragma unroll
            for (int d = 1; d < 16; d <<= 1) {
                int y = __shfl_up(s, d);
                if (lane >= d) s += y;
            }
            wsum[lane] = s;  // inclusive scan of wave sums
        }
        __syncthreads();
        int wave_off = (w > 0) ? wsum[w - 1] : 0;
        int excl = v + wave_off + carry - x;
        if (i < N_NODES) { row_off[i] = excl; cursor[i] = excl; }
        carry += wsum[15];
        __syncthreads();  // protect wsum before next chunk overwrites
    }
    if (t == 0) row_off[N_NODES] = carry;
}

__global__ __launch_bounds__(256) void bucket_kernel(
    const int* __restrict__ esrc, const int* __restrict__ edst,
    const float* __restrict__ evals, int* __restrict__ cursor,
    int* __restrict__ srt_src, float* __restrict__ srt_val)
{
    int e = blockIdx.x * 256 + threadIdx.x;
    if (e >= N_EDGES) return;
    int d = edst[e];
    int pos = atomicAdd(&cursor[d], 1);
    srt_src[pos] = esrc[e];
    srt_val[pos] = evals[e];
}

// ============ Phase 1: gather SpMM (one wave per node, no atomics) ============
__global__ __launch_bounds__(256) void gather_kernel(
    const int* __restrict__ row_off, const int* __restrict__ srt_src,
    const float* __restrict__ srt_val, const float* __restrict__ feats,
    float* __restrict__ LE)
{
    int gw = (blockIdx.x * 256 + threadIdx.x) >> 6;  // global wave = node
    int lane = threadIdx.x & 63;
    if (gw >= N_NODES) return;
    int beg = row_off[gw];
    int end = row_off[gw + 1];
    const float2* f2 = (const float2*)feats;
    float2 acc = {0.f, 0.f};
    int i = beg;
    for (; i + 1 < end; i += 2) {   // 2-edge unroll: two independent loads in flight
        int s0 = srt_src[i], s1 = srt_src[i + 1];
        float v0 = srt_val[i], v1 = srt_val[i + 1];
        float2 fa = f2[(size_t)s0 * 64 + lane];
        float2 fb = f2[(size_t)s1 * 64 + lane];
        acc.x += v0 * fa.x + v1 * fb.x;
        acc.y += v0 * fa.y + v1 * fb.y;
    }
    if (i < end) {
        int s0 = srt_src[i];
        float v0 = srt_val[i];
        float2 fa = f2[(size_t)s0 * 64 + lane];
        acc.x += v0 * fa.x;
        acc.y += v0 * fa.y;
    }
    ((float2*)LE)[(size_t)gw * 64 + lane] = acc;
}

// ============ Phase 2: fused dual dense layer (unchanged from R1) ============
#define NT 32
#define KC 16
#define WPAD 4

__global__ __launch_bounds__(256) void fused_mlp_kernel(
    const float* __restrict__ LE, const float* __restrict__ feats,
    const float* __restrict__ W1, const float* __restrict__ b1,
    const float* __restrict__ W2, const float* __restrict__ b2,
    float* __restrict__ out)
{
    __shared__ float sA[NT][F];
    __shared__ float sC[NT][F];
    __shared__ float sW1[KC][F + WPAD];
    __shared__ float sW2[KC][F + WPAD];

    const int t  = threadIdx.x;
    const int jt = t & 31;
    const int g  = t >> 5;
    const int node0 = blockIdx.x * NT;

    for (int i = t; i < NT * F; i += 256) {
        int nl = i >> 7;
        int k  = i & 127;
        int n  = node0 + nl;
        float le = 0.f, ft = 0.f;
        if (n < N_NODES) {
            le = LE[(size_t)n * F + k];
            ft = feats[(size_t)n * F + k];
        }
        sA[nl][k] = le + ft;
        sC[nl][k] = le * ft;
    }

    float acc[4][4];
#pragma unroll
    for (int a = 0; a < 4; a++)
#pragma unroll
        for (int b = 0; b < 4; b++) acc[a][b] = 0.f;

    for (int k0 = 0; k0 < F; k0 += KC) {
        __syncthreads();
        for (int i = t; i < KC * F; i += 256) {
            int j  = i >> 4;
            int kk = i & (KC - 1);
            sW1[kk][j] = W1[(size_t)j * F + k0 + kk];
            sW2[kk][j] = W2[(size_t)j * F + k0 + kk];
        }
        __syncthreads();

#pragma unroll
        for (int kk = 0; kk < KC; kk++) {
            const int k = k0 + kk;
            float4 w1 = *(const float4*)&sW1[kk][4 * jt];
            float4 w2 = *(const float4*)&sW2[kk][4 * jt];
#pragma unroll
            for (int nn = 0; nn < 4; nn++) {
                float a = sA[4 * g + nn][k];
                float c = sC[4 * g + nn][k];
                acc[nn][0] += a * w1.x + c * w2.x;
                acc[nn][1] += a * w1.y + c * w2.y;
                acc[nn][2] += a * w1.z + c * w2.z;
                acc[nn][3] += a * w1.w + c * w2.w;
            }
        }
    }

    const int j0 = 4 * jt;
    float4 bb;
    bb.x = b1[j0 + 0] + b2[j0 + 0];
    bb.y = b1[j0 + 1] + b2[j0 + 1];
    bb.z = b1[j0 + 2] + b2[j0 + 2];
    bb.w = b1[j0 + 3] + b2[j0 + 3];
#pragma unroll
    for (int nn = 0; nn < 4; nn++) {
        int n = node0 + 4 * g + nn;
        if (n < N_NODES) {
            float4 o;
            o.x = acc[nn][0] + bb.x;
            o.y = acc[nn][1] + bb.y;
            o.z = acc[nn][2] + bb.z;
            o.w = acc[nn][3] + bb.w;
            *(float4*)(out + (size_t)n * F + j0) = o;
        }
    }
}

extern "C" void kernel_launch(void* const* d_in, const int* in_sizes, int n_in,
                              void* d_out, int out_size, void* d_ws, size_t ws_size,
                              hipStream_t stream) {
    const int*   edge_src  = (const int*)d_in[0];
    const int*   edge_dst  = (const int*)d_in[1];
    const float* edge_vals = (const float*)d_in[2];
    const float* feats     = (const float*)d_in[3];
    const float* W1        = (const float*)d_in[4];
    const float* b1        = (const float*)d_in[5];
    const float* W2        = (const float*)d_in[6];
    const float* b2        = (const float*)d_in[7];
    float* out = (float*)d_out;

    // Workspace layout (bytes, 256-aligned):
    char* ws = (char*)d_ws;
    float* LE      = (float*)(ws);                              // 51,200,000
    int*   counts  = (int*)  (ws + 51200000);                   //    400,128
    int*   row_off = (int*)  (ws + 51600128);                   //    400,128 (N+1)
    int*   cursor  = (int*)  (ws + 52000256);                   //    400,000
    int*   srt_src = (int*)  (ws + 52400256);                   //  6,400,000
    float* srt_val = (float*)(ws + 58800256);                   //  6,400,000
                                                                // end: 65,200,256

    hipMemsetAsync(counts, 0, N_NODES * sizeof(int), stream);

    int eb = (N_EDGES + 255) / 256;
    hist_kernel<<<eb, 256, 0, stream>>>(edge_dst, counts);
    scan_kernel<<<1, 1024, 0, stream>>>(counts, row_off, cursor);
    bucket_kernel<<<eb, 256, 0, stream>>>(edge_src, edge_dst, edge_vals,
                                          cursor, srt_src, srt_val);

    int gwaves = N_NODES;                      // one wave per node
    int gb = (gwaves * 64 + 255) / 256;
    gather_kernel<<<gb, 256, 0, stream>>>(row_off, srt_src, srt_val, feats, LE);

    int mlp_blocks = (N_NODES + NT - 1) / NT;
    fused_mlp_kernel<<<mlp_blocks, 256, 0, stream>>>(LE, feats, W1, b1, W2, b2, out);
}

// Round 3
// 431.073 us; speedup vs baseline: 6.8743x; 1.5060x over previous
//
#include <hip/hip_runtime.h>

#define N_NODES 100000
#define N_EDGES 1600000
#define F 128
#define M_PAD 100032   // N_NODES rounded up to 64

typedef __attribute__((ext_vector_type(8))) short short8;
typedef __attribute__((ext_vector_type(4))) float float4v;

__device__ __forceinline__ unsigned pack_bf16(float x, float y) {
    unsigned ux = __float_as_uint(x), uy = __float_as_uint(y);
    ux = (ux + 0x7fffu + ((ux >> 16) & 1u)) >> 16;       // RNE
    uy = (uy + 0x7fffu + ((uy >> 16) & 1u)) >> 16;
    return ux | (uy << 16);
}

// ---- dtype prep ----
__global__ __launch_bounds__(256) void conv_feats(
    const float2* __restrict__ f, unsigned* __restrict__ o, int n2)
{
    int i = blockIdx.x * 256 + threadIdx.x;
    if (i < n2) { float2 v = f[i]; o[i] = pack_bf16(v.x, v.y); }
}

// Wb[j][0:128]=W1[j,:], Wb[j][128:256]=W2[j,:]  (bf16, as uint pairs)
__global__ __launch_bounds__(256) void conv_w(
    const float* __restrict__ W1, const float* __restrict__ W2,
    unsigned* __restrict__ Wbu)
{
    int i = blockIdx.x * 256 + threadIdx.x;     // 128*128 uint pairs
    if (i >= 128 * 128) return;
    int j = i >> 7, c = i & 127;
    const float* src = (c < 64) ? &W1[j * 128 + 2 * c] : &W2[j * 128 + 2 * (c - 64)];
    Wbu[i] = pack_bf16(src[0], src[1]);
}

// ---- CSR build ----
__global__ __launch_bounds__(256) void hist_kernel(
    const int* __restrict__ edst, int* __restrict__ counts)
{
    int e = blockIdx.x * 256 + threadIdx.x;
    if (e < N_EDGES) atomicAdd(&counts[edst[e]], 1);
}

// phase 1/3: per-block sums (98 blocks x 1024)
__global__ __launch_bounds__(1024) void scan_reduce(
    const int* __restrict__ counts, int* __restrict__ bsum)
{
    __shared__ int wsum[16];
    int t = threadIdx.x;
    int i = blockIdx.x * 1024 + t;
    int x = (i < N_NODES) ? counts[i] : 0;
#pragma unroll
    for (int d = 32; d > 0; d >>= 1) x += __shfl_down(x, d);
    if ((t & 63) == 0) wsum[t >> 6] = x;
    __syncthreads();
    if (t < 16) {
        int s = wsum[t];
#pragma unroll
        for (int d = 8; d > 0; d >>= 1) s += __shfl_down(s, d);
        if (t == 0) bsum[blockIdx.x] = s;
    }
}

// phase 2/3: exclusive scan of block sums (1 wave)
__global__ __launch_bounds__(64) void scan_partials(
    const int* __restrict__ bsum, int* __restrict__ bpre,
    int* __restrict__ row_off, int nb)
{
    int lane = threadIdx.x;
    int carry = 0;
    for (int base = 0; base < nb; base += 64) {
        int i = base + lane;
        int x = (i < nb) ? bsum[i] : 0;
        int v = x;
#pragma unroll
        for (int d = 1; d < 64; d <<= 1) {
            int y = __shfl_up(v, d);
            if (lane >= d) v += y;
        }
        if (i < nb) bpre[i] = v - x + carry;
        carry += __shfl(v, 63);
    }
    if (lane == 0) row_off[N_NODES] = carry;
}

// phase 3/3: block-local scan + global offset -> row_off, cursor
__global__ __launch_bounds__(1024) void scan_write(
    const int* __restrict__ counts, const int* __restrict__ bpre,
    int* __restrict__ row_off, int* __restrict__ cursor)
{
    __shared__ int wsum[16];
    int t = threadIdx.x, lane = t & 63, w = t >> 6;
    int i = blockIdx.x * 1024 + t;
    int x = (i < N_NODES) ? counts[i] : 0;
    int v = x;
#pragma unroll
    for (int d = 1; d < 64; d <<= 1) {
        int y = __shfl_up(v, d);
        if (lane >= d) v += y;
    }
    if (lane == 63) wsum[w] = v;
    __syncthreads();
    if (t < 16) {
        int s = wsum[t];
#pragma unroll
        for (int d = 1; d < 16; d <<= 1) {
            int y = __shfl_up(s, d);
            if (t >= d) s += y;
        }
        wsum[t] = s;
    }
    __syncthreads();
    int off = bpre[blockIdx.x] + (w ? wsum[w - 1] : 0);
    if (i < N_NODES) { int e = off + v - x; row_off[i] = e; cursor[i] = e; }
}

__global__ __launch_bounds__(256) void bucket_kernel(
    const int* __restrict__ esrc, const int* __restrict__ edst,
    const float* __restrict__ evals, int* __restrict__ cursor,
    int2* __restrict__ srt)
{
    int e = blockIdx.x * 256 + threadIdx.x;
    if (e >= N_EDGES) return;
    int pos = atomicAdd(&cursor[edst[e]], 1);
    srt[pos] = make_int2(esrc[e], __float_as_int(evals[e]));
}

// ---- gather SpMM: one wave/node, bf16 feats in, bf16 Abig out ----
// Abig[n][0:128] = LE+f (bf16), Abig[n][128:256] = LE*f (bf16)
__global__ __launch_bounds__(256) void gather_kernel(
    const int* __restrict__ row_off, const int2* __restrict__ srt,
    const unsigned* __restrict__ fb,   // feats bf16, 64 uints/row
    unsigned* __restrict__ Abig)       // 128 uints/row
{
    int node = (blockIdx.x * 256 + threadIdx.x) >> 6;
    int lane = threadIdx.x & 63;
    if (node >= N_NODES) return;
    int beg = row_off[node], end = row_off[node + 1];
    float ax = 0.f, ay = 0.f;
    int i = beg;
    for (; i + 3 < end; i += 4) {
        int2 e0 = srt[i], e1 = srt[i + 1], e2 = srt[i + 2], e3 = srt[i + 3];
        unsigned p0 = fb[(size_t)e0.x * 64 + lane];
        unsigned p1 = fb[(size_t)e1.x * 64 + lane];
        unsigned p2 = fb[(size_t)e2.x * 64 + lane];
        unsigned p3 = fb[(size_t)e3.x * 64 + lane];
        float v0 = __int_as_float(e0.y), v1 = __int_as_float(e1.y);
        float v2 = __int_as_float(e2.y), v3 = __int_as_float(e3.y);
        ax += v0 * __uint_as_float(p0 << 16) + v1 * __uint_as_float(p1 << 16);
        ay += v0 * __uint_as_float(p0 & 0xffff0000u) + v1 * __uint_as_float(p1 & 0xffff0000u);
        ax += v2 * __uint_as_float(p2 << 16) + v3 * __uint_as_float(p3 << 16);
        ay += v2 * __uint_as_float(p2 & 0xffff0000u) + v3 * __uint_as_float(p3 & 0xffff0000u);
    }
    for (; i < end; i++) {
        int2 e0 = srt[i];
        unsigned p0 = fb[(size_t)e0.x * 64 + lane];
        float v0 = __int_as_float(e0.y);
        ax += v0 * __uint_as_float(p0 << 16);
        ay += v0 * __uint_as_float(p0 & 0xffff0000u);
    }
    unsigned pf = fb[(size_t)node * 64 + lane];
    float fx = __uint_as_float(pf << 16);
    float fy = __uint_as_float(pf & 0xffff0000u);
    Abig[(size_t)node * 128 + lane]      = pack_bf16(ax + fx, ay + fy);
    Abig[(size_t)node * 128 + 64 + lane] = pack_bf16(ax * fx, ay * fy);
}

// ---- MFMA GEMM: out[M_PAD x 128] = Abig[M x 256] @ Wb[128 x 256]^T + b1 + b2
__global__ __launch_bounds__(256) void gemm_kernel(
    const unsigned short* __restrict__ Abig, const unsigned short* __restrict__ Wb,
    const float* __restrict__ b1, const float* __restrict__ b2,
    float* __restrict__ out)
{
    __shared__ unsigned short sW[128][264];  // +8 bf16 pad: 2-way-max LDS banks
    const int t = threadIdx.x;
    for (int i = t; i < 128 * 32; i += 256) {   // stage all of Wb (64 KB)
        int j = i >> 5, c = i & 31;
        *(uint4*)&sW[j][c * 8] = *(const uint4*)&Wb[j * 256 + c * 8];
    }
    __syncthreads();
    const int w = t >> 6, lane = t & 63;
    const int m0 = blockIdx.x * 64 + w * 16;
    const int col = lane & 15;
    const int quad = lane >> 4;
    const int ko = quad * 8;
    float4v acc[8];
#pragma unroll
    for (int j = 0; j < 8; j++) acc[j] = (float4v)(0.f);
    const unsigned short* arow = Abig + (size_t)(m0 + col) * 256 + ko;
#pragma unroll
    for (int k0 = 0; k0 < 8; k0++) {
        short8 a = *(const short8*)(arow + k0 * 32);
#pragma unroll
        for (int j = 0; j < 8; j++) {
            short8 b = *(const short8*)&sW[j * 16 + col][k0 * 32 + ko];
            acc[j] = __builtin_amdgcn_mfma_f32_16x16x32_bf16(a, b, acc[j], 0, 0, 0);
        }
    }
#pragma unroll
    for (int j = 0; j < 8; j++) {
        int n0 = j * 16 + col;
        float bb = b1[n0] + b2[n0];
#pragma unroll
        for (int r = 0; r < 4; r++) {
            int m = m0 + quad * 4 + r;
            if (m < N_NODES)
                out[(size_t)m * F + n0] = acc[j][r] + bb;
        }
    }
}

extern "C" void kernel_launch(void* const* d_in, const int* in_sizes, int n_in,
                              void* d_out, int out_size, void* d_ws, size_t ws_size,
                              hipStream_t stream) {
    const int*   edge_src  = (const int*)d_in[0];
    const int*   edge_dst  = (const int*)d_in[1];
    const float* edge_vals = (const float*)d_in[2];
    const float* feats     = (const float*)d_in[3];
    const float* W1        = (const float*)d_in[4];
    const float* b1        = (const float*)d_in[5];
    const float* W2        = (const float*)d_in[6];
    const float* b2        = (const float*)d_in[7];
    float* out = (float*)d_out;

    // Workspace layout (bytes):
    char* ws = (char*)d_ws;
    unsigned short* Abig   = (unsigned short*)(ws);             // 51,216,384 (M_PAD*256*2)
    unsigned*       featsb = (unsigned*)(ws + 51216384);        // 25,600,000
    int2*           srt    = (int2*)    (ws + 76816384);        // 12,800,000
    int*            counts = (int*)     (ws + 89616384);        //    400,000
    int*            row_off= (int*)     (ws + 90016384);        //    400,128 (N+1)
    int*            cursor = (int*)     (ws + 90416512);        //    400,000
    int*            bsum   = (int*)     (ws + 90816512);        //        512
    int*            bpre   = (int*)     (ws + 90817024);        //        512
    unsigned*       Wbu    = (unsigned*)(ws + 90817536);        //     65,536
                                                                // end ~90.9 MB

    hipMemsetAsync(counts, 0, N_NODES * sizeof(int), stream);

    conv_feats<<<(6400000 + 255) / 256, 256, 0, stream>>>((const float2*)feats, featsb, 6400000);
    conv_w<<<(128 * 128 + 255) / 256, 256, 0, stream>>>(W1, W2, Wbu);

    int eb = (N_EDGES + 255) / 256;
    hist_kernel<<<eb, 256, 0, stream>>>(edge_dst, counts);

    int nb = (N_NODES + 1023) / 1024;   // 98
    scan_reduce<<<nb, 1024, 0, stream>>>(counts, bsum);
    scan_partials<<<1, 64, 0, stream>>>(bsum, bpre, row_off, nb);
    scan_write<<<nb, 1024, 0, stream>>>(counts, bpre, row_off, cursor);

    bucket_kernel<<<eb, 256, 0, stream>>>(edge_src, edge_dst, edge_vals, cursor, srt);

    gather_kernel<<<(N_NODES * 64 + 255) / 256, 256, 0, stream>>>(row_off, srt, featsb, (unsigned*)Abig);

    gemm_kernel<<<M_PAD / 64, 256, 0, stream>>>(Abig, (const unsigned short*)Wbu, b1, b2, out);
}

// Round 4
// 352.076 us; speedup vs baseline: 8.4168x; 1.2244x over previous
//
#include <hip/hip_runtime.h>

#define N_NODES 100000
#define N_EDGES 1600000
#define F 128
#define M_PAD 100032     // N_NODES rounded up to 64
#define NCB 391          // coarse buckets = ceil(N_NODES/256)
#define EPB 4096         // edges per pass-A block

typedef __attribute__((ext_vector_type(8))) short short8;
typedef __attribute__((ext_vector_type(4))) float float4v;

__device__ __forceinline__ unsigned pack_bf16(float x, float y) {
    unsigned ux = __float_as_uint(x), uy = __float_as_uint(y);
    ux = (ux + 0x7fffu + ((ux >> 16) & 1u)) >> 16;       // RNE
    uy = (uy + 0x7fffu + ((uy >> 16) & 1u)) >> 16;
    return ux | (uy << 16);
}

// ---- dtype prep ----
__global__ __launch_bounds__(256) void conv_feats(
    const float2* __restrict__ f, unsigned* __restrict__ o, int n2)
{
    int i = blockIdx.x * 256 + threadIdx.x;
    if (i < n2) { float2 v = f[i]; o[i] = pack_bf16(v.x, v.y); }
}

__global__ __launch_bounds__(256) void conv_w(
    const float* __restrict__ W1, const float* __restrict__ W2,
    unsigned* __restrict__ Wbu)
{
    int i = blockIdx.x * 256 + threadIdx.x;
    if (i >= 128 * 128) return;
    int j = i >> 7, c = i & 127;
    const float* src = (c < 64) ? &W1[j * 128 + 2 * c] : &W2[j * 128 + 2 * (c - 64)];
    Wbu[i] = pack_bf16(src[0], src[1]);
}

// ---- CSR build ----
__global__ __launch_bounds__(256) void hist_kernel(
    const int* __restrict__ edst, int* __restrict__ counts)
{
    int e = blockIdx.x * 256 + threadIdx.x;
    if (e < N_EDGES) atomicAdd(&counts[edst[e]], 1);
}

__global__ __launch_bounds__(1024) void scan_reduce(
    const int* __restrict__ counts, int* __restrict__ bsum)
{
    __shared__ int wsum[16];
    int t = threadIdx.x;
    int i = blockIdx.x * 1024 + t;
    int x = (i < N_NODES) ? counts[i] : 0;
#pragma unroll
    for (int d = 32; d > 0; d >>= 1) x += __shfl_down(x, d);
    if ((t & 63) == 0) wsum[t >> 6] = x;
    __syncthreads();
    if (t < 16) {
        int s = wsum[t];
#pragma unroll
        for (int d = 8; d > 0; d >>= 1) s += __shfl_down(s, d);
        if (t == 0) bsum[blockIdx.x] = s;
    }
}

__global__ __launch_bounds__(64) void scan_partials(
    const int* __restrict__ bsum, int* __restrict__ bpre,
    int* __restrict__ row_off, int nb)
{
    int lane = threadIdx.x;
    int carry = 0;
    for (int base = 0; base < nb; base += 64) {
        int i = base + lane;
        int x = (i < nb) ? bsum[i] : 0;
        int v = x;
#pragma unroll
        for (int d = 1; d < 64; d <<= 1) {
            int y = __shfl_up(v, d);
            if (lane >= d) v += y;
        }
        if (i < nb) bpre[i] = v - x + carry;
        carry += __shfl(v, 63);
    }
    if (lane == 0) row_off[N_NODES] = carry;
}

// block-local scan + global offset -> row_off; also init coarse cursors
__global__ __launch_bounds__(1024) void scan_write(
    const int* __restrict__ counts, const int* __restrict__ bpre,
    int* __restrict__ row_off, int* __restrict__ ccur)
{
    __shared__ int wsum[16];
    int t = threadIdx.x, lane = t & 63, w = t >> 6;
    int i = blockIdx.x * 1024 + t;
    int x = (i < N_NODES) ? counts[i] : 0;
    int v = x;
#pragma unroll
    for (int d = 1; d < 64; d <<= 1) {
        int y = __shfl_up(v, d);
        if (lane >= d) v += y;
    }
    if (lane == 63) wsum[w] = v;
    __syncthreads();
    if (t < 16) {
        int s = wsum[t];
#pragma unroll
        for (int d = 1; d < 16; d <<= 1) {
            int y = __shfl_up(s, d);
            if (t >= d) s += y;
        }
        wsum[t] = s;
    }
    __syncthreads();
    int off = bpre[blockIdx.x] + (w ? wsum[w - 1] : 0);
    if (i < N_NODES) {
        int e = off + v - x;
        row_off[i] = e;
        if ((i & 255) == 0) ccur[i >> 8] = e;   // coarse bucket base
    }
}

// ---- Pass A: coarse multisplit (bucket = dst>>8), run-coalesced writes ----
__global__ __launch_bounds__(256) void passA_kernel(
    const int* __restrict__ esrc, const int* __restrict__ edst,
    const float* __restrict__ evals, int* __restrict__ ccur,
    int2* __restrict__ srtA, unsigned char* __restrict__ dlA)
{
    __shared__ int2 sv[EPB];              // 32 KB
    __shared__ unsigned short bkt[EPB];   //  8 KB
    __shared__ unsigned char dll[EPB];    //  4 KB
    __shared__ int h[NCB], lo[NCB], gbase[NCB];

    const int t = threadIdx.x;
    const int base = blockIdx.x * EPB;
    const int cnt = min(EPB, N_EDGES - base);

    for (int i = t; i < NCB; i += 256) h[i] = 0;
    __syncthreads();

    int rsrc[16], rdst[16], rrank[16];
    float rval[16];
#pragma unroll
    for (int i = 0; i < 16; i++) {
        int e = base + i * 256 + t;
        if (e < N_EDGES) {
            rsrc[i] = esrc[e];
            rdst[i] = edst[e];
            rval[i] = evals[e];
            rrank[i] = atomicAdd(&h[rdst[i] >> 8], 1);
        } else rdst[i] = -1;
    }
    __syncthreads();

    // exclusive scan of h[0..NCB) by wave 0
    if (t < 64) {
        int carry = 0;
        for (int b0 = 0; b0 < NCB; b0 += 64) {
            int i = b0 + t;
            int x = (i < NCB) ? h[i] : 0;
            int v = x;
#pragma unroll
            for (int d = 1; d < 64; d <<= 1) {
                int y = __shfl_up(v, d);
                if (t >= d) v += y;
            }
            if (i < NCB) lo[i] = v - x + carry;
            carry += __shfl(v, 63);
        }
    }
    __syncthreads();

    // place into LDS in bucket-grouped order
#pragma unroll
    for (int i = 0; i < 16; i++) {
        if (rdst[i] >= 0) {
            int b = rdst[i] >> 8;
            int s = lo[b] + rrank[i];
            sv[s]  = make_int2(rsrc[i], __float_as_int(rval[i]));
            bkt[s] = (unsigned short)b;
            dll[s] = (unsigned char)(rdst[i] & 255);
        }
    }
    // claim global runs
    for (int b = t; b < NCB; b += 256) {
        int c = h[b];
        if (c) gbase[b] = atomicAdd(&ccur[b], c);
    }
    __syncthreads();

    // coalesced copy-out (consecutive slots -> consecutive positions)
    for (int s = t; s < cnt; s += 256) {
        int b = bkt[s];
        int pos = gbase[b] + (s - lo[b]);
        srtA[pos] = sv[s];
        dlA[pos]  = dll[s];
    }
}

// ---- Pass B: per-bucket node sort; scattered writes stay in one XCD's L2 ----
__global__ __launch_bounds__(256) void passB_kernel(
    const int* __restrict__ row_off, const int2* __restrict__ srtA,
    const unsigned char* __restrict__ dlA, int2* __restrict__ srt)
{
    __shared__ int cur[256];
    const int t = threadIdx.x;
    const int node0 = blockIdx.x << 8;
    int n = node0 + t;
    if (n <= N_NODES) cur[t] = row_off[n < N_NODES ? n : N_NODES];
    const int rs = row_off[node0];
    const int re = row_off[min(node0 + 256, N_NODES)];
    __syncthreads();
    for (int idx = rs + t; idx < re; idx += 256) {
        int2 e = srtA[idx];
        int d = dlA[idx];
        int pos = atomicAdd(&cur[d], 1);
        srt[pos] = e;
    }
}

// ---- gather SpMM: one wave/node, bf16 feats in, bf16 Abig out ----
__global__ __launch_bounds__(256) void gather_kernel(
    const int* __restrict__ row_off, const int2* __restrict__ srt,
    const unsigned* __restrict__ fb, unsigned* __restrict__ Abig)
{
    int node = (blockIdx.x * 256 + threadIdx.x) >> 6;
    int lane = threadIdx.x & 63;
    if (node >= N_NODES) return;
    int beg = row_off[node], end = row_off[node + 1];
    float ax = 0.f, ay = 0.f;
    int i = beg;
    for (; i + 3 < end; i += 4) {
        int2 e0 = srt[i], e1 = srt[i + 1], e2 = srt[i + 2], e3 = srt[i + 3];
        unsigned p0 = fb[(size_t)e0.x * 64 + lane];
        unsigned p1 = fb[(size_t)e1.x * 64 + lane];
        unsigned p2 = fb[(size_t)e2.x * 64 + lane];
        unsigned p3 = fb[(size_t)e3.x * 64 + lane];
        float v0 = __int_as_float(e0.y), v1 = __int_as_float(e1.y);
        float v2 = __int_as_float(e2.y), v3 = __int_as_float(e3.y);
        ax += v0 * __uint_as_float(p0 << 16) + v1 * __uint_as_float(p1 << 16);
        ay += v0 * __uint_as_float(p0 & 0xffff0000u) + v1 * __uint_as_float(p1 & 0xffff0000u);
        ax += v2 * __uint_as_float(p2 << 16) + v3 * __uint_as_float(p3 << 16);
        ay += v2 * __uint_as_float(p2 & 0xffff0000u) + v3 * __uint_as_float(p3 & 0xffff0000u);
    }
    for (; i < end; i++) {
        int2 e0 = srt[i];
        unsigned p0 = fb[(size_t)e0.x * 64 + lane];
        float v0 = __int_as_float(e0.y);
        ax += v0 * __uint_as_float(p0 << 16);
        ay += v0 * __uint_as_float(p0 & 0xffff0000u);
    }
    unsigned pf = fb[(size_t)node * 64 + lane];
    float fx = __uint_as_float(pf << 16);
    float fy = __uint_as_float(pf & 0xffff0000u);
    Abig[(size_t)node * 128 + lane]      = pack_bf16(ax + fx, ay + fy);
    Abig[(size_t)node * 128 + 64 + lane] = pack_bf16(ax * fx, ay * fy);
}

// ---- MFMA GEMM: out = Abig[M x 256] @ Wb[128 x 256]^T + b1 + b2 ----
__global__ __launch_bounds__(256) void gemm_kernel(
    const unsigned short* __restrict__ Abig, const unsigned short* __restrict__ Wb,
    const float* __restrict__ b1, const float* __restrict__ b2,
    float* __restrict__ out)
{
    __shared__ unsigned short sW[128][264];
    const int t = threadIdx.x;
    for (int i = t; i < 128 * 32; i += 256) {
        int j = i >> 5, c = i & 31;
        *(uint4*)&sW[j][c * 8] = *(const uint4*)&Wb[j * 256 + c * 8];
    }
    __syncthreads();
    const int w = t >> 6, lane = t & 63;
    const int m0 = blockIdx.x * 64 + w * 16;
    const int col = lane & 15;
    const int quad = lane >> 4;
    const int ko = quad * 8;
    float4v acc[8];
#pragma unroll
    for (int j = 0; j < 8; j++) acc[j] = (float4v)(0.f);
    const unsigned short* arow = Abig + (size_t)(m0 + col) * 256 + ko;
#pragma unroll
    for (int k0 = 0; k0 < 8; k0++) {
        short8 a = *(const short8*)(arow + k0 * 32);
#pragma unroll
        for (int j = 0; j < 8; j++) {
            short8 b = *(const short8*)&sW[j * 16 + col][k0 * 32 + ko];
            acc[j] = __builtin_amdgcn_mfma_f32_16x16x32_bf16(a, b, acc[j], 0, 0, 0);
        }
    }
#pragma unroll
    for (int j = 0; j < 8; j++) {
        int n0 = j * 16 + col;
        float bb = b1[n0] + b2[n0];
#pragma unroll
        for (int r = 0; r < 4; r++) {
            int m = m0 + quad * 4 + r;
            if (m < N_NODES)
                out[(size_t)m * F + n0] = acc[j][r] + bb;
        }
    }
}

extern "C" void kernel_launch(void* const* d_in, const int* in_sizes, int n_in,
                              void* d_out, int out_size, void* d_ws, size_t ws_size,
                              hipStream_t stream) {
    const int*   edge_src  = (const int*)d_in[0];
    const int*   edge_dst  = (const int*)d_in[1];
    const float* edge_vals = (const float*)d_in[2];
    const float* feats     = (const float*)d_in[3];
    const float* W1        = (const float*)d_in[4];
    const float* b1        = (const float*)d_in[5];
    const float* W2        = (const float*)d_in[6];
    const float* b2        = (const float*)d_in[7];
    float* out = (float*)d_out;

    // Workspace layout (bytes). srtA/dlA alias the Abig region: they are dead
    // before gather_kernel writes Abig.
    char* ws = (char*)d_ws;
    unsigned short* Abig   = (unsigned short*)(ws);             // 51,216,384
    int2*           srtA   = (int2*)          (ws);             // 12,800,000 (alias)
    unsigned char*  dlA    = (unsigned char*) (ws + 12800000);  //  1,600,000 (alias)
    unsigned*       featsb = (unsigned*)(ws + 51216384);        // 25,600,000
    int2*           srt    = (int2*)    (ws + 76816384);        // 12,800,000
    int*            counts = (int*)     (ws + 89616384);        //    400,000
    int*            row_off= (int*)     (ws + 90016384);        //    400,128
    int*            ccur   = (int*)     (ws + 90416512);        //      2,048
    int*            bsum   = (int*)     (ws + 90418560);        //        512
    int*            bpre   = (int*)     (ws + 90419072);        //        512
    unsigned*       Wbu    = (unsigned*)(ws + 90419584);        //     65,536

    hipMemsetAsync(counts, 0, N_NODES * sizeof(int), stream);

    conv_feats<<<(6400000 + 255) / 256, 256, 0, stream>>>((const float2*)feats, featsb, 6400000);
    conv_w<<<(128 * 128 + 255) / 256, 256, 0, stream>>>(W1, W2, Wbu);

    int eb = (N_EDGES + 255) / 256;
    hist_kernel<<<eb, 256, 0, stream>>>(edge_dst, counts);

    int nb = (N_NODES + 1023) / 1024;
    scan_reduce<<<nb, 1024, 0, stream>>>(counts, bsum);
    scan_partials<<<1, 64, 0, stream>>>(bsum, bpre, row_off, nb);
    scan_write<<<nb, 1024, 0, stream>>>(counts, bpre, row_off, ccur);

    passA_kernel<<<(N_EDGES + EPB - 1) / EPB, 256, 0, stream>>>(
        edge_src, edge_dst, edge_vals, ccur, srtA, dlA);
    passB_kernel<<<NCB, 256, 0, stream>>>(row_off, srtA, dlA, srt);

    gather_kernel<<<(N_NODES * 64 + 255) / 256, 256, 0, stream>>>(row_off, srt, featsb, (unsigned*)Abig);

    gemm_kernel<<<M_PAD / 64, 256, 0, stream>>>(Abig, (const unsigned short*)Wbu, b1, b2, out);
}

// Round 5
// 345.559 us; speedup vs baseline: 8.5755x; 1.0189x over previous
//
#include <hip/hip_runtime.h>

#define N_NODES 100000
#define N_EDGES 1600000
#define F 128
#define NCB 391          // coarse buckets = ceil(N_NODES/256)
#define EPB 4096         // edges per pass-A block
#define FB_BLOCKS 25000  // conv feats: 6.4M uint pairs / 256
#define W_BLOCKS 64      // conv w: 16384 / 256
#define H_BLOCKS 6250    // hist: 1.6M / 256

typedef __attribute__((ext_vector_type(8))) short short8;
typedef __attribute__((ext_vector_type(4))) float float4v;

__device__ __forceinline__ unsigned pack_bf16(float x, float y) {
    unsigned ux = __float_as_uint(x), uy = __float_as_uint(y);
    ux = (ux + 0x7fffu + ((ux >> 16) & 1u)) >> 16;       // RNE
    uy = (uy + 0x7fffu + ((uy >> 16) & 1u)) >> 16;
    return ux | (uy << 16);
}

// ---- fused prep: feats->bf16, W->Wb bf16, dst histogram ----
__global__ __launch_bounds__(256) void prep_kernel(
    const float2* __restrict__ feats2, unsigned* __restrict__ featsb,
    const float* __restrict__ W1, const float* __restrict__ W2,
    unsigned* __restrict__ Wbu,
    const int* __restrict__ edst, int* __restrict__ counts)
{
    int b = blockIdx.x, t = threadIdx.x;
    if (b < FB_BLOCKS) {
        int i = b * 256 + t;                       // < 6,400,000 exactly
        float2 v = feats2[i];
        featsb[i] = pack_bf16(v.x, v.y);
    } else if (b < FB_BLOCKS + W_BLOCKS) {
        int i = (b - FB_BLOCKS) * 256 + t;         // < 16384 exactly
        int j = i >> 7, c = i & 127;
        const float* s = (c < 64) ? &W1[j * 128 + 2 * c] : &W2[j * 128 + 2 * (c - 64)];
        Wbu[i] = pack_bf16(s[0], s[1]);
    } else {
        int e = (b - FB_BLOCKS - W_BLOCKS) * 256 + t;
        if (e < N_EDGES) atomicAdd(&counts[edst[e]], 1);
    }
}

// ---- scan (3-phase) ----
__global__ __launch_bounds__(1024) void scan_reduce(
    const int* __restrict__ counts, int* __restrict__ bsum)
{
    __shared__ int wsum[16];
    int t = threadIdx.x;
    int i = blockIdx.x * 1024 + t;
    int x = (i < N_NODES) ? counts[i] : 0;
#pragma unroll
    for (int d = 32; d > 0; d >>= 1) x += __shfl_down(x, d);
    if ((t & 63) == 0) wsum[t >> 6] = x;
    __syncthreads();
    if (t < 16) {
        int s = wsum[t];
#pragma unroll
        for (int d = 8; d > 0; d >>= 1) s += __shfl_down(s, d);
        if (t == 0) bsum[blockIdx.x] = s;
    }
}

__global__ __launch_bounds__(64) void scan_partials(
    const int* __restrict__ bsum, int* __restrict__ bpre,
    int* __restrict__ row_off, int nb)
{
    int lane = threadIdx.x;
    int carry = 0;
    for (int base = 0; base < nb; base += 64) {
        int i = base + lane;
        int x = (i < nb) ? bsum[i] : 0;
        int v = x;
#pragma unroll
        for (int d = 1; d < 64; d <<= 1) {
            int y = __shfl_up(v, d);
            if (lane >= d) v += y;
        }
        if (i < nb) bpre[i] = v - x + carry;
        carry += __shfl(v, 63);
    }
    if (lane == 0) row_off[N_NODES] = carry;
}

__global__ __launch_bounds__(1024) void scan_write(
    const int* __restrict__ counts, const int* __restrict__ bpre,
    int* __restrict__ row_off, int* __restrict__ ccur)
{
    __shared__ int wsum[16];
    int t = threadIdx.x, lane = t & 63, w = t >> 6;
    int i = blockIdx.x * 1024 + t;
    int x = (i < N_NODES) ? counts[i] : 0;
    int v = x;
#pragma unroll
    for (int d = 1; d < 64; d <<= 1) {
        int y = __shfl_up(v, d);
        if (lane >= d) v += y;
    }
    if (lane == 63) wsum[w] = v;
    __syncthreads();
    if (t < 16) {
        int s = wsum[t];
#pragma unroll
        for (int d = 1; d < 16; d <<= 1) {
            int y = __shfl_up(s, d);
            if (t >= d) s += y;
        }
        wsum[t] = s;
    }
    __syncthreads();
    int off = bpre[blockIdx.x] + (w ? wsum[w - 1] : 0);
    if (i < N_NODES) {
        int e = off + v - x;
        row_off[i] = e;
        if ((i & 255) == 0) ccur[i >> 8] = e;
    }
}

// ---- Pass A: coarse multisplit; dst-low packed into srtA.x bits 24..31 ----
__global__ __launch_bounds__(256) void passA_kernel(
    const int* __restrict__ esrc, const int* __restrict__ edst,
    const float* __restrict__ evals, int* __restrict__ ccur,
    int2* __restrict__ srtA)
{
    __shared__ int2 sv[EPB];              // 32 KB
    __shared__ unsigned short bkt[EPB];   //  8 KB
    __shared__ int h[NCB], lo[NCB], gbase[NCB];

    const int t = threadIdx.x;
    const int base = blockIdx.x * EPB;
    const int cnt = min(EPB, N_EDGES - base);

    for (int i = t; i < NCB; i += 256) h[i] = 0;
    __syncthreads();

    int rsrc[16], rdst[16], rrank[16];
    float rval[16];
#pragma unroll
    for (int i = 0; i < 16; i++) {
        int e = base + i * 256 + t;
        if (e < N_EDGES) {
            rsrc[i] = esrc[e];
            rdst[i] = edst[e];
            rval[i] = evals[e];
            rrank[i] = atomicAdd(&h[rdst[i] >> 8], 1);
        } else rdst[i] = -1;
    }
    __syncthreads();

    if (t < 64) {   // exclusive scan of h by wave 0
        int carry = 0;
        for (int b0 = 0; b0 < NCB; b0 += 64) {
            int i = b0 + t;
            int x = (i < NCB) ? h[i] : 0;
            int v = x;
#pragma unroll
            for (int d = 1; d < 64; d <<= 1) {
                int y = __shfl_up(v, d);
                if (t >= d) v += y;
            }
            if (i < NCB) lo[i] = v - x + carry;
            carry += __shfl(v, 63);
        }
    }
    __syncthreads();

#pragma unroll
    for (int i = 0; i < 16; i++) {
        if (rdst[i] >= 0) {
            int b = rdst[i] >> 8;
            int s = lo[b] + rrank[i];
            sv[s]  = make_int2(rsrc[i] | ((rdst[i] & 255) << 24),
                               __float_as_int(rval[i]));
            bkt[s] = (unsigned short)b;
        }
    }
    for (int b = t; b < NCB; b += 256) {
        int c = h[b];
        if (c) gbase[b] = atomicAdd(&ccur[b], c);
    }
    __syncthreads();

    for (int s = t; s < cnt; s += 256) {
        int b = bkt[s];
        srtA[gbase[b] + (s - lo[b])] = sv[s];
    }
}

// ---- Pass B: per-bucket node sort (writes stay in one L2 window) ----
__global__ __launch_bounds__(1024) void passB_kernel(
    const int* __restrict__ row_off, const int2* __restrict__ srtA,
    int2* __restrict__ srt)
{
    __shared__ int cur[256];
    const int t = threadIdx.x;
    const int node0 = blockIdx.x << 8;
    if (t < 256) cur[t] = row_off[min(node0 + t, N_NODES)];
    const int rs = row_off[node0];
    const int re = row_off[min(node0 + 256, N_NODES)];
    __syncthreads();
    for (int idx = rs + t; idx < re; idx += 1024) {
        int2 e = srtA[idx];
        int d = (unsigned)e.x >> 24;
        int pos = atomicAdd(&cur[d], 1);
        srt[pos] = make_int2(e.x & 0x00FFFFFF, e.y);
    }
}

// ---- Fused gather + GEMM: 128 nodes/block, zero barriers ----
// Gather: wave w builds LDS A-tile rows w*16..w*16+15 (bf16, cols 0..127 = LE+f,
// 128..255 = LE*f), 4 nodes in parallel (16 lanes x float4 per feats row).
// GEMM: same wave MFMAs its own rows; B-fragments straight from L2-hot Wb.
__global__ __launch_bounds__(512, 4) void fused_gg(
    const int* __restrict__ row_off, const int2* __restrict__ srt,
    const float4* __restrict__ fb4, const unsigned short* __restrict__ Wb,
    const float* __restrict__ b1, const float* __restrict__ b2,
    float* __restrict__ out)
{
    __shared__ unsigned short sA[128][264];   // 67.6 KB -> 2 blocks/CU
    const int t = threadIdx.x;
    const int w = t >> 6;          // wave 0..7
    const int lane = t & 63;
    const int grp = lane >> 4;     // node-subgroup 0..3
    const int c16 = lane & 15;     // 16B chunk of the 256B feats row
    const int node0 = blockIdx.x * 128;
    const int rbase = node0 + w * 16;

    // ================= gather phase =================
    for (int g4 = 0; g4 < 4; g4++) {
        const int row = w * 16 + g4 * 4 + grp;
        const int n = node0 + row;
        const int nc = min(n, N_NODES - 1);
        const int beg = row_off[min(n, N_NODES)];
        const int end = row_off[min(n + 1, N_NODES)];
        const int d = end - beg;
        int dm = d;
        dm = max(dm, __shfl_xor(dm, 16));
        dm = max(dm, __shfl_xor(dm, 32));   // wave-uniform max degree

        float a[8];
#pragma unroll
        for (int q = 0; q < 8; q++) a[q] = 0.f;

        int step = 0;
        for (; step + 3 < dm; step += 4) {
            int2 e0 = srt[min(beg + step + 0, N_EDGES - 1)];
            int2 e1 = srt[min(beg + step + 1, N_EDGES - 1)];
            int2 e2 = srt[min(beg + step + 2, N_EDGES - 1)];
            int2 e3 = srt[min(beg + step + 3, N_EDGES - 1)];
            bool a0 = step + 0 < d, a1 = step + 1 < d;
            bool a2 = step + 2 < d, a3 = step + 3 < d;
            int   x0 = a0 ? e0.x : 0,  x1 = a1 ? e1.x : 0;
            int   x2 = a2 ? e2.x : 0,  x3 = a3 ? e3.x : 0;
            float v0 = a0 ? __int_as_float(e0.y) : 0.f;
            float v1 = a1 ? __int_as_float(e1.y) : 0.f;
            float v2 = a2 ? __int_as_float(e2.y) : 0.f;
            float v3 = a3 ? __int_as_float(e3.y) : 0.f;
            float4 p0 = fb4[(size_t)x0 * 16 + c16];
            float4 p1 = fb4[(size_t)x1 * 16 + c16];
            float4 p2 = fb4[(size_t)x2 * 16 + c16];
            float4 p3 = fb4[(size_t)x3 * 16 + c16];
#pragma unroll
            for (int u = 0; u < 4; u++) {
                unsigned q0 = __float_as_uint((&p0.x)[u]);
                unsigned q1 = __float_as_uint((&p1.x)[u]);
                unsigned q2 = __float_as_uint((&p2.x)[u]);
                unsigned q3 = __float_as_uint((&p3.x)[u]);
                a[2*u]   += v0 * __uint_as_float(q0 << 16)
                          + v1 * __uint_as_float(q1 << 16)
                          + v2 * __uint_as_float(q2 << 16)
                          + v3 * __uint_as_float(q3 << 16);
                a[2*u+1] += v0 * __uint_as_float(q0 & 0xffff0000u)
                          + v1 * __uint_as_float(q1 & 0xffff0000u)
                          + v2 * __uint_as_float(q2 & 0xffff0000u)
                          + v3 * __uint_as_float(q3 & 0xffff0000u);
            }
        }
        for (; step < dm; step++) {
            int2 e0 = srt[min(beg + step, N_EDGES - 1)];
            bool a0 = step < d;
            int   x0 = a0 ? e0.x : 0;
            float v0 = a0 ? __int_as_float(e0.y) : 0.f;
            float4 p0 = fb4[(size_t)x0 * 16 + c16];
#pragma unroll
            for (int u = 0; u < 4; u++) {
                unsigned q0 = __float_as_uint((&p0.x)[u]);
                a[2*u]   += v0 * __uint_as_float(q0 << 16);
                a[2*u+1] += v0 * __uint_as_float(q0 & 0xffff0000u);
            }
        }

        // self feats row -> sum & product halves
        float4 pf = fb4[(size_t)nc * 16 + c16];
        float f[8];
#pragma unroll
        for (int u = 0; u < 4; u++) {
            unsigned q = __float_as_uint((&pf.x)[u]);
            f[2*u]   = __uint_as_float(q << 16);
            f[2*u+1] = __uint_as_float(q & 0xffff0000u);
        }
        uint4 S, P;
        S.x = pack_bf16(a[0]+f[0], a[1]+f[1]); S.y = pack_bf16(a[2]+f[2], a[3]+f[3]);
        S.z = pack_bf16(a[4]+f[4], a[5]+f[5]); S.w = pack_bf16(a[6]+f[6], a[7]+f[7]);
        P.x = pack_bf16(a[0]*f[0], a[1]*f[1]); P.y = pack_bf16(a[2]*f[2], a[3]*f[3]);
        P.z = pack_bf16(a[4]*f[4], a[5]*f[5]); P.w = pack_bf16(a[6]*f[6], a[7]*f[7]);
        *(uint4*)&sA[row][c16 * 8]       = S;
        *(uint4*)&sA[row][128 + c16 * 8] = P;
    }

    // ================= GEMM phase (reads only this wave's rows) =================
    const int col = c16;
    const int quad = grp;
    const int ko = quad * 8;
    const unsigned short* aptr = &sA[w * 16 + col][ko];

    float4v acc[8];
#pragma unroll
    for (int j = 0; j < 8; j++) acc[j] = (float4v)(0.f);

    short8 a_cur = *(const short8*)(aptr);
#pragma unroll
    for (int k0 = 0; k0 < 8; k0++) {
        short8 a_nxt;
        if (k0 < 7) a_nxt = *(const short8*)(aptr + (k0 + 1) * 32);
#pragma unroll
        for (int j = 0; j < 8; j++) {
            short8 b = *(const short8*)&Wb[(size_t)(j * 16 + col) * 256 + k0 * 32 + ko];
            acc[j] = __builtin_amdgcn_mfma_f32_16x16x32_bf16(a_cur, b, acc[j], 0, 0, 0);
        }
        if (k0 < 7) a_cur = a_nxt;
    }

#pragma unroll
    for (int j = 0; j < 8; j++) {
        int n0 = j * 16 + col;
        float bb = b1[n0] + b2[n0];
#pragma unroll
        for (int r = 0; r < 4; r++) {
            int m = rbase + quad * 4 + r;
            if (m < N_NODES)
                __builtin_nontemporal_store(acc[j][r] + bb, &out[(size_t)m * F + n0]);
        }
    }
}

extern "C" void kernel_launch(void* const* d_in, const int* in_sizes, int n_in,
                              void* d_out, int out_size, void* d_ws, size_t ws_size,
                              hipStream_t stream) {
    const int*   edge_src  = (const int*)d_in[0];
    const int*   edge_dst  = (const int*)d_in[1];
    const float* edge_vals = (const float*)d_in[2];
    const float* feats     = (const float*)d_in[3];
    const float* W1        = (const float*)d_in[4];
    const float* b1        = (const float*)d_in[5];
    const float* W2        = (const float*)d_in[6];
    const float* b2        = (const float*)d_in[7];
    float* out = (float*)d_out;

    char* ws = (char*)d_ws;
    unsigned* featsb  = (unsigned*)(ws);                 // 25,600,000
    int2*     srtA    = (int2*)    (ws + 25600000);      // 12,800,000
    int2*     srt     = (int2*)    (ws + 38400000);      // 12,800,000
    int*      counts  = (int*)     (ws + 51200000);      //    400,000
    int*      row_off = (int*)     (ws + 51600000);      //    400,128 (N+1)
    int*      ccur    = (int*)     (ws + 52000128);      //      2,048
    int*      bsum    = (int*)     (ws + 52002176);      //        512
    int*      bpre    = (int*)     (ws + 52002688);      //        512
    unsigned* Wbu     = (unsigned*)(ws + 52003200);      //     65,536

    hipMemsetAsync(counts, 0, N_NODES * sizeof(int), stream);

    prep_kernel<<<FB_BLOCKS + W_BLOCKS + H_BLOCKS, 256, 0, stream>>>(
        (const float2*)feats, featsb, W1, W2, Wbu, edge_dst, counts);

    int nb = (N_NODES + 1023) / 1024;   // 98
    scan_reduce<<<nb, 1024, 0, stream>>>(counts, bsum);
    scan_partials<<<1, 64, 0, stream>>>(bsum, bpre, row_off, nb);
    scan_write<<<nb, 1024, 0, stream>>>(counts, bpre, row_off, ccur);

    passA_kernel<<<(N_EDGES + EPB - 1) / EPB, 256, 0, stream>>>(
        edge_src, edge_dst, edge_vals, ccur, srtA);
    passB_kernel<<<NCB, 1024, 0, stream>>>(row_off, srtA, srt);

    fused_gg<<<(N_NODES + 127) / 128, 512, 0, stream>>>(
        row_off, srt, (const float4*)featsb, (const unsigned short*)Wbu,
        b1, b2, out);
}

// Round 6
// 284.246 us; speedup vs baseline: 10.4253x; 1.2157x over previous
//
#include <hip/hip_runtime.h>

#define N_NODES 100000
#define N_EDGES 1600000
#define F 128
#define M_PAD 100032       // N_NODES rounded up to 64
#define NCB 391            // coarse buckets = ceil(N_NODES/256)
#define CAP 8192           // padded bucket capacity (max real ~4350)
#define EPB 4096           // edges per pass-A block
#define FB_BLOCKS 25000    // feats conv: 6.4M uint pairs / 256
#define W_BLOCKS 64        // W conv: 16384 / 256

typedef __attribute__((ext_vector_type(8))) short short8;
typedef __attribute__((ext_vector_type(4))) float float4v;

__device__ __forceinline__ unsigned pack_bf16(float x, float y) {
    unsigned ux = __float_as_uint(x), uy = __float_as_uint(y);
    ux = (ux + 0x7fffu + ((ux >> 16) & 1u)) >> 16;       // RNE
    uy = (uy + 0x7fffu + ((uy >> 16) & 1u)) >> 16;
    return ux | (uy << 16);
}

// ---- prep: feats->bf16, W->Wb bf16, ccur init (no hist, no memset) ----
__global__ __launch_bounds__(256) void prep_kernel(
    const float2* __restrict__ feats2, unsigned* __restrict__ featsb,
    const float* __restrict__ W1, const float* __restrict__ W2,
    unsigned* __restrict__ Wbu, int* __restrict__ ccur)
{
    int b = blockIdx.x, t = threadIdx.x;
    if (b < FB_BLOCKS) {
        int i = b * 256 + t;                       // < 6,400,000 exactly
        float2 v = feats2[i];
        featsb[i] = pack_bf16(v.x, v.y);
    } else if (b < FB_BLOCKS + W_BLOCKS) {
        int i = (b - FB_BLOCKS) * 256 + t;         // < 16384 exactly
        int j = i >> 7, c = i & 127;
        const float* s = (c < 64) ? &W1[j * 128 + 2 * c] : &W2[j * 128 + 2 * (c - 64)];
        Wbu[i] = pack_bf16(s[0], s[1]);
    } else {
        int i = (b - FB_BLOCKS - W_BLOCKS) * 256 + t;
        if (i < NCB) ccur[i] = i * CAP;
    }
}

// ---- Pass A: coarse multisplit into padded buckets; dst-low in bits 24..31 ----
__global__ __launch_bounds__(256) void passA_kernel(
    const int* __restrict__ esrc, const int* __restrict__ edst,
    const float* __restrict__ evals, int* __restrict__ ccur,
    int2* __restrict__ srtA)
{
    __shared__ int2 sv[EPB];              // 32 KB
    __shared__ unsigned short bkt[EPB];   //  8 KB
    __shared__ int h[NCB], lo[NCB], gbase[NCB];

    const int t = threadIdx.x;
    const int base = blockIdx.x * EPB;
    const int cnt = min(EPB, N_EDGES - base);

    for (int i = t; i < NCB; i += 256) h[i] = 0;
    __syncthreads();

    int rsrc[16], rdst[16], rrank[16];
    float rval[16];
#pragma unroll
    for (int i = 0; i < 16; i++) {
        int e = base + i * 256 + t;
        if (e < N_EDGES) {
            rsrc[i] = esrc[e];
            rdst[i] = edst[e];
            rval[i] = evals[e];
            rrank[i] = atomicAdd(&h[rdst[i] >> 8], 1);
        } else rdst[i] = -1;
    }
    __syncthreads();

    if (t < 64) {   // exclusive scan of h by wave 0
        int carry = 0;
        for (int b0 = 0; b0 < NCB; b0 += 64) {
            int i = b0 + t;
            int x = (i < NCB) ? h[i] : 0;
            int v = x;
#pragma unroll
            for (int d = 1; d < 64; d <<= 1) {
                int y = __shfl_up(v, d);
                if (t >= d) v += y;
            }
            if (i < NCB) lo[i] = v - x + carry;
            carry += __shfl(v, 63);
        }
    }
    __syncthreads();

#pragma unroll
    for (int i = 0; i < 16; i++) {
        if (rdst[i] >= 0) {
            int b = rdst[i] >> 8;
            int s = lo[b] + rrank[i];
            sv[s]  = make_int2(rsrc[i] | ((rdst[i] & 255) << 24),
                               __float_as_int(rval[i]));
            bkt[s] = (unsigned short)b;
        }
    }
    for (int b = t; b < NCB; b += 256) {
        int c = h[b];
        if (c) gbase[b] = atomicAdd(&ccur[b], c);
    }
    __syncthreads();

    for (int s = t; s < cnt; s += 256) {
        int b = bkt[s];
        srtA[gbase[b] + (s - lo[b])] = sv[s];
    }
}

// ---- Pass B: per-bucket fine sort + per-node {beg,end} (replaces hist+scan) ----
__global__ __launch_bounds__(1024) void passB_kernel(
    const int* __restrict__ ccur, const int2* __restrict__ srtA,
    int2* __restrict__ srt, int2* __restrict__ bege)
{
    __shared__ int hist[256], excl[256], cur[256];
    const int t = threadIdx.x;
    const int b = blockIdx.x;
    const int base = b * CAP;
    const int cnt = ccur[b] - base;

    if (t < 256) hist[t] = 0;
    __syncthreads();
    for (int idx = t; idx < cnt; idx += 1024)
        atomicAdd(&hist[(unsigned)srtA[base + idx].x >> 24], 1);
    __syncthreads();
    if (t < 64) {    // exclusive scan of hist[256] by wave 0
        int carry = 0;
#pragma unroll
        for (int c = 0; c < 4; c++) {
            int i = c * 64 + t;
            int x = hist[i];
            int v = x;
#pragma unroll
            for (int d = 1; d < 64; d <<= 1) {
                int y = __shfl_up(v, d);
                if (t >= d) v += y;
            }
            excl[i] = v - x + carry;
            carry += __shfl(v, 63);
        }
    }
    __syncthreads();
    if (t < 256) {
        int n = (b << 8) + t;
        if (n < N_NODES) {
            int bg = base + excl[t];
            bege[n] = make_int2(bg, bg + hist[t]);
            cur[t] = bg;
        }
    }
    __syncthreads();
    for (int idx = t; idx < cnt; idx += 1024) {
        int2 e = srtA[base + idx];        // L2-hot re-read
        int d = (unsigned)e.x >> 24;
        int pos = atomicAdd(&cur[d], 1);
        srt[pos] = make_int2(e.x & 0x00FFFFFF, e.y);
    }
}

// ---- gather SpMM: 2 nodes/wave (32 lanes each), 0 LDS, bf16 Abig out ----
__global__ __launch_bounds__(256) void gather_kernel(
    const int2* __restrict__ bege, const int2* __restrict__ srt,
    const uint2* __restrict__ fb2,    // feats bf16, 32 uint2/row
    uint2* __restrict__ Abig2)        // 64 uint2/row (sum half, prod half)
{
    const int gw = (blockIdx.x * 256 + threadIdx.x) >> 6;   // wave id
    const int lane = threadIdx.x & 63;
    const int node = gw * 2 + (lane >> 5);                  // 2 nodes per wave
    const int l = lane & 31;
    if (node >= N_NODES) return;

    int2 be = bege[node];
    int i = be.x;
    const int end = be.y;

    float a0 = 0.f, a1 = 0.f, a2 = 0.f, a3 = 0.f;
    for (; i + 3 < end; i += 4) {
        int2 e0 = srt[i], e1 = srt[i + 1], e2 = srt[i + 2], e3 = srt[i + 3];
        uint2 p0 = fb2[(size_t)e0.x * 32 + l];
        uint2 p1 = fb2[(size_t)e1.x * 32 + l];
        uint2 p2 = fb2[(size_t)e2.x * 32 + l];
        uint2 p3 = fb2[(size_t)e3.x * 32 + l];
        float v0 = __int_as_float(e0.y), v1 = __int_as_float(e1.y);
        float v2 = __int_as_float(e2.y), v3 = __int_as_float(e3.y);
        a0 += v0 * __uint_as_float(p0.x << 16) + v1 * __uint_as_float(p1.x << 16)
            + v2 * __uint_as_float(p2.x << 16) + v3 * __uint_as_float(p3.x << 16);
        a1 += v0 * __uint_as_float(p0.x & 0xffff0000u) + v1 * __uint_as_float(p1.x & 0xffff0000u)
            + v2 * __uint_as_float(p2.x & 0xffff0000u) + v3 * __uint_as_float(p3.x & 0xffff0000u);
        a2 += v0 * __uint_as_float(p0.y << 16) + v1 * __uint_as_float(p1.y << 16)
            + v2 * __uint_as_float(p2.y << 16) + v3 * __uint_as_float(p3.y << 16);
        a3 += v0 * __uint_as_float(p0.y & 0xffff0000u) + v1 * __uint_as_float(p1.y & 0xffff0000u)
            + v2 * __uint_as_float(p2.y & 0xffff0000u) + v3 * __uint_as_float(p3.y & 0xffff0000u);
    }
    for (; i < end; i++) {
        int2 e0 = srt[i];
        uint2 p0 = fb2[(size_t)e0.x * 32 + l];
        float v0 = __int_as_float(e0.y);
        a0 += v0 * __uint_as_float(p0.x << 16);
        a1 += v0 * __uint_as_float(p0.x & 0xffff0000u);
        a2 += v0 * __uint_as_float(p0.y << 16);
        a3 += v0 * __uint_as_float(p0.y & 0xffff0000u);
    }

    uint2 pf = fb2[(size_t)node * 32 + l];
    float f0 = __uint_as_float(pf.x << 16);
    float f1 = __uint_as_float(pf.x & 0xffff0000u);
    float f2v = __uint_as_float(pf.y << 16);
    float f3 = __uint_as_float(pf.y & 0xffff0000u);

    uint2 S, P;
    S.x = pack_bf16(a0 + f0, a1 + f1);  S.y = pack_bf16(a2 + f2v, a3 + f3);
    P.x = pack_bf16(a0 * f0, a1 * f1);  P.y = pack_bf16(a2 * f2v, a3 * f3);
    Abig2[(size_t)node * 64 + l]      = S;
    Abig2[(size_t)node * 64 + 32 + l] = P;
}

// ---- GEMM: out = Abig[M x 256] @ Wb[128 x 256]^T + b1 + b2 (no LDS, no barrier)
__global__ __launch_bounds__(256) void gemm_kernel(
    const unsigned short* __restrict__ Abig, const unsigned short* __restrict__ Wb,
    const float* __restrict__ b1, const float* __restrict__ b2,
    float* __restrict__ out)
{
    const int t = threadIdx.x;
    const int w = t >> 6, lane = t & 63;
    const int col = lane & 15;
    const int quad = lane >> 4;
    const int ko = quad * 8;
    const int m0 = blockIdx.x * 64 + w * 16;

    float4v acc[8];
#pragma unroll
    for (int j = 0; j < 8; j++) acc[j] = (float4v)(0.f);

    const unsigned short* arow = Abig + (size_t)(m0 + col) * 256 + ko;
#pragma unroll
    for (int k0 = 0; k0 < 8; k0++) {
        short8 a = *(const short8*)(arow + k0 * 32);
#pragma unroll
        for (int j = 0; j < 8; j++) {
            short8 b = *(const short8*)&Wb[(size_t)(j * 16 + col) * 256 + k0 * 32 + ko];
            acc[j] = __builtin_amdgcn_mfma_f32_16x16x32_bf16(a, b, acc[j], 0, 0, 0);
        }
    }

#pragma unroll
    for (int j = 0; j < 8; j++) {
        int n0 = j * 16 + col;
        float bb = b1[n0] + b2[n0];
#pragma unroll
        for (int r = 0; r < 4; r++) {
            int m = m0 + quad * 4 + r;
            if (m < N_NODES)
                __builtin_nontemporal_store(acc[j][r] + bb, &out[(size_t)m * F + n0]);
        }
    }
}

extern "C" void kernel_launch(void* const* d_in, const int* in_sizes, int n_in,
                              void* d_out, int out_size, void* d_ws, size_t ws_size,
                              hipStream_t stream) {
    const int*   edge_src  = (const int*)d_in[0];
    const int*   edge_dst  = (const int*)d_in[1];
    const float* edge_vals = (const float*)d_in[2];
    const float* feats     = (const float*)d_in[3];
    const float* W1        = (const float*)d_in[4];
    const float* b1        = (const float*)d_in[5];
    const float* W2        = (const float*)d_in[6];
    const float* b2        = (const float*)d_in[7];
    float* out = (float*)d_out;

    // Workspace layout (bytes):
    char* ws = (char*)d_ws;
    unsigned*       featsb = (unsigned*)      (ws);             // 25,600,000
    int2*           srtA   = (int2*)          (ws + 25600000);  // 25,624,576 (391*8192*8)
    int2*           srt    = (int2*)          (ws + 51224576);  // 25,624,576
    int2*           bege   = (int2*)          (ws + 76849152);  //    800,000
    int*            ccur   = (int*)           (ws + 77649152);  //      2,048
    unsigned*       Wbu    = (unsigned*)      (ws + 77651200);  //     65,536
    unsigned short* Abig   = (unsigned short*)(ws + 77716736);  // 51,216,384 (M_PAD*256*2)
                                                                // end ~128.9 MB

    prep_kernel<<<FB_BLOCKS + W_BLOCKS + 2, 256, 0, stream>>>(
        (const float2*)feats, featsb, W1, W2, Wbu, ccur);

    passA_kernel<<<(N_EDGES + EPB - 1) / EPB, 256, 0, stream>>>(
        edge_src, edge_dst, edge_vals, ccur, srtA);

    passB_kernel<<<NCB, 1024, 0, stream>>>(ccur, srtA, srt, bege);

    gather_kernel<<<(N_NODES / 2 * 64 + 255) / 256, 256, 0, stream>>>(
        bege, srt, (const uint2*)featsb, (uint2*)Abig);

    gemm_kernel<<<M_PAD / 64, 256, 0, stream>>>(
        Abig, (const unsigned short*)Wbu, b1, b2, out);
}